// Round 7
// baseline (599.985 us; speedup 1.0000x reference)
//
#include <hip/hip_runtime.h>
#include <hip/hip_bf16.h>

typedef float  f32x4  __attribute__((ext_vector_type(4)));
typedef short  bf16x8 __attribute__((ext_vector_type(8)));
typedef short  bf16x4 __attribute__((ext_vector_type(4)));

typedef const void __attribute__((address_space(1))) gv_t;
typedef void __attribute__((address_space(3))) sv_t;

namespace {

constexpr int B_ = 2;
constexpr int S_ = 1024;
constexpr int H_ = 1024;
constexpr int V_ = 50257;
constexpr int M_ = B_ * S_;          // 2048
constexpr int VP2_ = 50432;          // 197*256, zero-padded W_lm rows (fast path)
constexpr int VP1_ = 50304;          // 393*128 (mid path)
constexpr float DT_ = 0.1f;
constexpr float THRESH_ = 10.0f;

constexpr int BK = 64;
constexpr int NT = H_ / BK;          // 16 K-tiles

__device__ __forceinline__ unsigned short f2bf(float f) {
  union { float f; unsigned u; } x;
  x.f = f;
  x.u += 0x7FFFu + ((x.u >> 16) & 1u);   // RNE (no NaNs in this problem)
  return (unsigned short)(x.u >> 16);
}

// ---------------- Kernel 1: hidden f32 -> bf16, fused with impulse dot
__global__ void cvt_hidden_impulse_kernel(const float* __restrict__ hidden,
                                          const float* __restrict__ W_imp,
                                          const float* __restrict__ b_imp,
                                          unsigned short* __restrict__ hid_bf,
                                          float* __restrict__ imp) {
  const int m = blockIdx.x;
  const int t = threadIdx.x;
  const float4 hv = reinterpret_cast<const float4*>(hidden + (size_t)m * H_)[t];
  const float4 wv = reinterpret_cast<const float4*>(W_imp)[t];   // row 0
  bf16x4 o;
  o[0] = (short)f2bf(hv.x); o[1] = (short)f2bf(hv.y);
  o[2] = (short)f2bf(hv.z); o[3] = (short)f2bf(hv.w);
  *(bf16x4*)(hid_bf + (size_t)m * H_ + t * 4) = o;
  float p = hv.x * wv.x + hv.y * wv.y + hv.z * wv.z + hv.w * wv.w;
  #pragma unroll
  for (int off = 32; off; off >>= 1) p += __shfl_down(p, off);
  __shared__ float partial[4];
  if ((t & 63) == 0) partial[t >> 6] = p;
  __syncthreads();
  if (t == 0) {
    const float v = partial[0] + partial[1] + partial[2] + partial[3] + b_imp[0];
    const int b = m >> 10;
    const int s = m & (S_ - 1);
    imp[s * B_ + b] = v;
  }
}

// ---------------- scan body
__device__ __forceinline__ void scan_body(const float* __restrict__ imp_s,
                                          const float* __restrict__ ttu_state,
                                          const float* __restrict__ ttu_params,
                                          float* __restrict__ states,
                                          float* __restrict__ final_out, int t) {
  if (t < B_) {
    const float gamma   = ttu_params[0];
    const float alpha_c = ttu_params[1];
    const float beta_c  = ttu_params[2];
    const float delta   = ttu_params[3];
    const float alpha_d = ttu_params[4];
    const float epsilon = ttu_params[5];
    const float alpha_m = ttu_params[6];
    float c = ttu_state[t * 3 + 0];
    float d = ttu_state[t * 3 + 1];
    float m = ttu_state[t * 3 + 2];
    for (int s = 0; s < S_; ++s) {
      const float ii = imp_s[s * B_ + t];
      const float dc = gamma * ii - alpha_c * c - beta_c * c * d;
      const float dd = delta * c * c - alpha_d * d;
      const float dm = epsilon * d - alpha_m * m;
      c = c + DT_ * dc;
      float nd = d + DT_ * dd;
      m = m + DT_ * dm;
      nd = (fabsf(nd) > THRESH_ ? 0.5f : 1.0f) * nd;
      d = nd;
      float* st = states + (size_t)(s * B_ + t) * 3;
      st[0] = c; st[1] = d; st[2] = m;
    }
    final_out[t * 3 + 0] = c;
    final_out[t * 3 + 1] = d;
    final_out[t * 3 + 2] = m;
  }
}

__global__ void ttu_scan_kernel(const float* __restrict__ imp,
                                const float* __restrict__ ttu_state,
                                const float* __restrict__ ttu_params,
                                float* __restrict__ states,
                                float* __restrict__ final_out) {
  __shared__ float imp_s[S_ * B_];
  const int t = threadIdx.x;  // 64
  for (int i = t; i < S_ * B_; i += 64) imp_s[i] = imp[i];
  __syncthreads();
  scan_body(imp_s, ttu_state, ttu_params, states, final_out, t);
}

// ---------------- Kernel 2.5: W_lm f32 -> bf16 + fused scan (last block)
__global__ void cvt_wlm_scan_kernel(const float* __restrict__ src,
                                    unsigned short* __restrict__ dst,
                                    long n_src, long n_dst,
                                    const float* __restrict__ imp,
                                    const float* __restrict__ ttu_state,
                                    const float* __restrict__ ttu_params,
                                    float* __restrict__ states,
                                    float* __restrict__ final_out) {
  __shared__ float imp_s[S_ * B_];
  const int t = threadIdx.x;   // 256
  if (blockIdx.x == gridDim.x - 1) {
    for (int i = t; i < S_ * B_; i += 256) imp_s[i] = imp[i];
    __syncthreads();
    scan_body(imp_s, ttu_state, ttu_params, states, final_out, t);
    return;
  }
  const long stride = (long)(gridDim.x - 1) * blockDim.x * 8;
  for (long i = ((long)blockIdx.x * blockDim.x + t) * 8; i < n_dst; i += stride) {
    bf16x8 v;
    if (i < n_src) {
      const float4 a = *(const float4*)(src + i);
      const float4 b = *(const float4*)(src + i + 4);
      v[0] = (short)f2bf(a.x); v[1] = (short)f2bf(a.y);
      v[2] = (short)f2bf(a.z); v[3] = (short)f2bf(a.w);
      v[4] = (short)f2bf(b.x); v[5] = (short)f2bf(b.y);
      v[6] = (short)f2bf(b.z); v[7] = (short)f2bf(b.w);
    } else {
      v = (bf16x8){0, 0, 0, 0, 0, 0, 0, 0};
    }
    *(bf16x8*)(dst + i) = v;
  }
}

__global__ void cvt_bf16_kernel(const float* __restrict__ src,
                                unsigned short* __restrict__ dst,
                                long n_src, long n_dst) {
  const long stride = (long)gridDim.x * blockDim.x * 8;
  for (long i = ((long)blockIdx.x * blockDim.x + threadIdx.x) * 8; i < n_dst; i += stride) {
    bf16x8 v;
    if (i < n_src) {
      const float4 a = *(const float4*)(src + i);
      const float4 b = *(const float4*)(src + i + 4);
      v[0] = (short)f2bf(a.x); v[1] = (short)f2bf(a.y);
      v[2] = (short)f2bf(a.z); v[3] = (short)f2bf(a.w);
      v[4] = (short)f2bf(b.x); v[5] = (short)f2bf(b.y);
      v[6] = (short)f2bf(b.z); v[7] = (short)f2bf(b.w);
    } else {
      v = (bf16x8){0, 0, 0, 0, 0, 0, 0, 0};
    }
    *(bf16x8*)(dst + i) = v;
  }
}

// ======================= fast GEMM: 256x256, 4-phase/K-tile (m201 pattern) ===
// Per phase: {ds_read own A-quad; stage 1 half of kt+1; [vmcnt]; bar;
//             lgkmcnt(0); sched_barrier; setprio1; 16 MFMA; setprio0; bar}.
// B-frags of a tile live in REGISTERS, read once at p3 of the previous tile
// (post-barrier, lgkmcnt(8): the 4 A-q3 reads drained, 8 B reads in flight).
// Stage order of tile kt+1 during kt: B0@p0, B1@p1, A-lo@p2, A-hi@p3 where
// A-lo = rows {0-63, 128-191} (both wave-rows' quads 0-1), A-hi = the rest.
// Per-wave FIFO ledger (2 loads/stage), steady state entering p0(kt) with
// outstanding {A-hi(kt)}:
//   p0: +B0 -> vmcnt(2) drains A-hi(kt)   [p2/p3 read A-q2/3 in A-hi(kt)]
//   p1: +B1 -> (no wait)
//   p2: +A-lo -> vmcnt(2) drains B0,B1    [p3 post-bar reads B-frags(kt+1)]
//   p3: +A-hi -> vmcnt(2) drains A-lo     [p0(kt+1) reads A-q0 in A-lo(kt+1)]
// Never vmcnt(0) mid-loop. Last tile: vmcnt(0) once at p0 (2 loads out).
// LDS chunk-XOR swizzle as R2-R6 (BANK_CONFLICT==0 verified): LDS[r][c16] =
// G[r][c16 ^ (r&7)] via pre-swizzled source (linear dest, rule #21).
#define VMCNT(N) asm volatile("s_waitcnt vmcnt(" #N ")" ::: "memory")
#define LGK(N)   asm volatile("s_waitcnt lgkmcnt(" #N ")" ::: "memory")
#define BAR()    asm volatile("s_barrier" ::: "memory")
#define SB0()    __builtin_amdgcn_sched_barrier(0)

__global__ __launch_bounds__(512, 2) void ttu_gemm_bf16_256p4_kernel(
    const unsigned short* __restrict__ Ab,   // hidden bf16 [M_][H_]
    const unsigned short* __restrict__ Bb,   // W_lm bf16 [VP2_][H_]
    const float* __restrict__ states,
    const float* __restrict__ Wmod,
    float* __restrict__ out)
{
  __shared__ unsigned short A_s[2][256 * BK];   // 64 KiB
  __shared__ unsigned short B_s[2][256 * BK];   // 64 KiB
  __shared__ float st_s[256][3];
  __shared__ float wm_s[256][3];

  const int t = threadIdx.x;
  const int cpx = gridDim.x >> 3;              // 197; grid 1576 % 8 == 0
  const int bid = (blockIdx.x & 7) * cpx + (blockIdx.x >> 3);
  const int mb = bid & 7;                      // M fastest: share B-panel
  const int nb = bid >> 3;
  const int m0 = mb * 256;
  const int n0 = nb * 256;

  if (t < 256) {
    const int m = m0 + t;
    const int b = m >> 10;
    const int s = m & (S_ - 1);
    const float* st = states + (size_t)(s * B_ + b) * 3;
    st_s[t][0] = st[0]; st_s[t][1] = st[1]; st_s[t][2] = st[2];
  } else {
    const int tt = t - 256;
    const int n = n0 + tt;
    const bool ok = n < V_;
    wm_s[tt][0] = ok ? Wmod[n * 3 + 0] : 0.f;
    wm_s[tt][1] = ok ? Wmod[n * 3 + 1] : 0.f;
    wm_s[tt][2] = ok ? Wmod[n * 3 + 2] : 0.f;
  }

  const int lane = t & 63;
  const int wid  = t >> 6;             // 8 waves
  const int lr   = lane >> 3;          // staging sub-row 0..7
  const int ch   = lane & 7;           // staging 16B chunk 0..7
  const int wmi  = wid >> 2;           // wave row 0..1 (128 rows each)
  const int wni  = wid & 3;            // wave col 0..3 (64 cols each)
  const int lm   = lane & 15;
  const int kg   = lane >> 4;

  const unsigned short* Abase = Ab + (size_t)m0 * H_;
  const unsigned short* Bbase = Bb + (size_t)n0 * H_;

  // Precomputed per-lane stage offsets (elements) + LDS element bases.
  // B half h, instr n: rows h*128 + wid*16 + n*8 (+lr), natural LDS rows.
  // A group g (0=lo,1=hi), instr n: idx = wid*16+n*8; row_base =
  //   g*64 + (idx&63) + ((idx>>6)<<7); covers lo={0-63,128-191}, hi=rest.
  size_t bgo[2][2]; int bro[2][2];
  size_t ago[2][2]; int aro[2][2];
  #pragma unroll
  for (int h = 0; h < 2; ++h)
    #pragma unroll
    for (int n = 0; n < 2; ++n) {
      const int rb = h * 128 + wid * 16 + n * 8;
      const int r  = rb + lr;
      bro[h][n] = rb * BK;
      bgo[h][n] = (size_t)r * H_ + ((ch ^ (r & 7)) << 3);
    }
  #pragma unroll
  for (int g = 0; g < 2; ++g)
    #pragma unroll
    for (int n = 0; n < 2; ++n) {
      const int ib = wid * 16 + n * 8;
      const int rb = g * 64 + (ib & 63) + ((ib >> 6) << 7);
      const int r  = rb + lr;
      aro[g][n] = rb * BK;
      ago[g][n] = (size_t)r * H_ + ((ch ^ (r & 7)) << 3);
    }

#define STG_B(BUF, H, K0) do {                                                 \
    __builtin_amdgcn_global_load_lds((gv_t*)(Bbase + bgo[H][0] + (K0)),        \
                                     (sv_t*)((BUF) + bro[H][0]), 16, 0, 0);    \
    __builtin_amdgcn_global_load_lds((gv_t*)(Bbase + bgo[H][1] + (K0)),        \
                                     (sv_t*)((BUF) + bro[H][1]), 16, 0, 0);    \
  } while (0)
#define STG_A(BUF, G, K0) do {                                                 \
    __builtin_amdgcn_global_load_lds((gv_t*)(Abase + ago[G][0] + (K0)),        \
                                     (sv_t*)((BUF) + aro[G][0]), 16, 0, 0);    \
    __builtin_amdgcn_global_load_lds((gv_t*)(Abase + ago[G][1] + (K0)),        \
                                     (sv_t*)((BUF) + aro[G][1]), 16, 0, 0);    \
  } while (0)
#define RD_AQ(AS, Q) do {                                                      \
    _Pragma("unroll") for (int i2_ = 0; i2_ < 2; ++i2_) {                      \
      const int r_ = wmi * 128 + ((Q) * 2 + i2_) * 16 + lm;                    \
      _Pragma("unroll") for (int ks_ = 0; ks_ < 2; ++ks_)                      \
        af[i2_][ks_] = *(const bf16x8*)&(AS)[r_ * BK +                         \
                        (((ks_ * 4 + kg) ^ (r_ & 7)) << 3)];                   \
    }                                                                          \
  } while (0)
#define RD_BF(BF, BS) do {                                                     \
    _Pragma("unroll") for (int j_ = 0; j_ < 4; ++j_) {                         \
      const int r_ = wni * 64 + j_ * 16 + lm;                                  \
      _Pragma("unroll") for (int ks_ = 0; ks_ < 2; ++ks_)                      \
        BF[j_][ks_] = *(const bf16x8*)&(BS)[r_ * BK +                          \
                       (((ks_ * 4 + kg) ^ (r_ & 7)) << 3)];                    \
    }                                                                          \
  } while (0)
#define MFMA_Q(Q, BF) do {                                                     \
    __builtin_amdgcn_s_setprio(1);                                             \
    _Pragma("unroll") for (int ks_ = 0; ks_ < 2; ++ks_)                        \
      _Pragma("unroll") for (int i2_ = 0; i2_ < 2; ++i2_)                      \
        _Pragma("unroll") for (int j_ = 0; j_ < 4; ++j_)                       \
          acc[(Q) * 2 + i2_][j_] = __builtin_amdgcn_mfma_f32_16x16x32_bf16(    \
              af[i2_][ks_], BF[j_][ks_], acc[(Q) * 2 + i2_][j_], 0, 0, 0);     \
    __builtin_amdgcn_s_setprio(0);                                             \
  } while (0)
#define DO_TILE(KT, AS, BS, ASN, BSN, BFC, BFN, ISLAST) do {                   \
    const int k0n_ = ((KT) + 1) * BK;                                          \
    /* p0 */                                                                   \
    RD_AQ(AS, 0);                                                              \
    if (!(ISLAST)) { STG_B(BSN, 0, k0n_); VMCNT(2); } else { VMCNT(0); }       \
    BAR(); LGK(0); SB0(); MFMA_Q(0, BFC); BAR();                               \
    /* p1 */                                                                   \
    RD_AQ(AS, 1);                                                              \
    if (!(ISLAST)) { STG_B(BSN, 1, k0n_); }                                    \
    BAR(); LGK(0); SB0(); MFMA_Q(1, BFC); BAR();                               \
    /* p2 */                                                                   \
    RD_AQ(AS, 2);                                                              \
    if (!(ISLAST)) { STG_A(ASN, 0, k0n_); VMCNT(2); }                          \
    BAR(); LGK(0); SB0(); MFMA_Q(2, BFC); BAR();                               \
    /* p3 */                                                                   \
    RD_AQ(AS, 3);                                                              \
    if (!(ISLAST)) { STG_A(ASN, 1, k0n_); VMCNT(2); }                          \
    BAR();                                                                     \
    if (!(ISLAST)) { RD_BF(BFN, BSN); LGK(8); } else { LGK(0); }               \
    SB0(); MFMA_Q(3, BFC); BAR();                                              \
  } while (0)

  f32x4 acc[8][4];
  #pragma unroll
  for (int i = 0; i < 8; ++i)
    #pragma unroll
    for (int j = 0; j < 4; ++j)
      acc[i][j] = (f32x4){0.f, 0.f, 0.f, 0.f};

  bf16x8 bfA[4][2], bfB[4][2], af[2][2];

  // prologue: tile 0 -> buf0; vmcnt(2) leaves A-hi(t0) in flight (invariant)
  STG_B(&B_s[0][0], 0, 0);
  STG_B(&B_s[0][0], 1, 0);
  STG_A(&A_s[0][0], 0, 0);
  STG_A(&A_s[0][0], 1, 0);
  VMCNT(2);
  BAR();
  RD_BF(bfA, &B_s[0][0]);   // drained by p0's lgkmcnt(0)

  #pragma unroll 1
  for (int ktp = 0; ktp < NT / 2; ++ktp) {
    const int kt = ktp * 2;
    DO_TILE(kt,     &A_s[0][0], &B_s[0][0], &A_s[1][0], &B_s[1][0], bfA, bfB, false);
    DO_TILE(kt + 1, &A_s[1][0], &B_s[1][0], &A_s[0][0], &B_s[0][0], bfB, bfA, ktp == NT / 2 - 1);
  }

  // Epilogue: += 0.1 * states . W_mod^T; row-major store order
  #pragma unroll
  for (int i = 0; i < 8; ++i) {
    #pragma unroll
    for (int rr = 0; rr < 4; ++rr) {
      const int mloc = wmi * 128 + i * 16 + kg * 4 + rr;
      const float s0 = st_s[mloc][0], s1 = st_s[mloc][1], s2 = st_s[mloc][2];
      float* orow = out + (size_t)(m0 + mloc) * V_ + n0;
      #pragma unroll
      for (int j = 0; j < 4; ++j) {
        const int nloc = wni * 64 + j * 16 + lm;
        if (n0 + nloc < V_) {
          const float corr = 0.1f * (s0 * wm_s[nloc][0] + s1 * wm_s[nloc][1] + s2 * wm_s[nloc][2]);
          orow[nloc] = acc[i][j][rr] + corr;
        }
      }
    }
  }
#undef STG_B
#undef STG_A
#undef RD_AQ
#undef RD_BF
#undef MFMA_Q
#undef DO_TILE
}

// ---------------- Mid fallback: 128x128 2-phase double-buffer (R3)
__global__ __launch_bounds__(256) void ttu_gemm_bf16_db_kernel(
    const unsigned short* __restrict__ Ab,
    const unsigned short* __restrict__ Bb,   // [VP1_][H_]
    const float* __restrict__ states,
    const float* __restrict__ Wmod,
    float* __restrict__ out)
{
  __shared__ unsigned short AB_s[2][2][128 * BK];
  __shared__ float st_s[128][3];
  __shared__ float wm_s[128][3];

  const int t = threadIdx.x;
  const int cpx = gridDim.x >> 3;
  const int bid = (blockIdx.x & 7) * cpx + (blockIdx.x >> 3);
  const int mb = bid & 15;
  const int nb = bid >> 4;
  const int m0 = mb * 128;
  const int n0 = nb * 128;

  if (t < 128) {
    const int m = m0 + t;
    const int b = m >> 10;
    const int s = m & (S_ - 1);
    const float* st = states + (size_t)(s * B_ + b) * 3;
    st_s[t][0] = st[0]; st_s[t][1] = st[1]; st_s[t][2] = st[2];
  } else {
    const int tt = t - 128;
    const int n = n0 + tt;
    const bool ok = n < V_;
    wm_s[tt][0] = ok ? Wmod[n * 3 + 0] : 0.f;
    wm_s[tt][1] = ok ? Wmod[n * 3 + 1] : 0.f;
    wm_s[tt][2] = ok ? Wmod[n * 3 + 2] : 0.f;
  }

  const int lane = t & 63;
  const int wid  = t >> 6;
  const int lr   = lane >> 3;
  const int ch   = lane & 7;
  const int wm   = wid >> 1;
  const int wn   = wid & 1;
  const int lm   = lane & 15;
  const int kg   = lane >> 4;

  const unsigned short* Abase = Ab + (size_t)m0 * H_;
  const unsigned short* Bbase = Bb + (size_t)n0 * H_;
  const int r0 = wid * 32;

  auto STAGE = [&](unsigned short* As, unsigned short* Bs, int kt) {
    const int k0 = kt * BK;
    #pragma unroll
    for (int ins = 0; ins < 4; ++ins) {
      const int lrow = r0 + ins * 8 + lr;
      const int sch  = ch ^ (lrow & 7);
      __builtin_amdgcn_global_load_lds(
          (gv_t*)(Abase + (size_t)lrow * H_ + k0 + sch * 8),
          (sv_t*)(As + (r0 + ins * 8) * BK), 16, 0, 0);
    }
    #pragma unroll
    for (int ins = 0; ins < 4; ++ins) {
      const int lrow = r0 + ins * 8 + lr;
      const int sch  = ch ^ (lrow & 7);
      __builtin_amdgcn_global_load_lds(
          (gv_t*)(Bbase + (size_t)lrow * H_ + k0 + sch * 8),
          (sv_t*)(Bs + (r0 + ins * 8) * BK), 16, 0, 0);
    }
  };

  f32x4 acc[4][4];
  #pragma unroll
  for (int i = 0; i < 4; ++i)
    #pragma unroll
    for (int j = 0; j < 4; ++j)
      acc[i][j] = (f32x4){0.f, 0.f, 0.f, 0.f};

  unsigned short* Ac = &AB_s[0][0][0];
  unsigned short* Bc = &AB_s[0][1][0];
  unsigned short* An = &AB_s[1][0][0];
  unsigned short* Bn = &AB_s[1][1][0];

  STAGE(Ac, Bc, 0);
  __syncthreads();

  for (int kt = 0; kt < NT; ++kt) {
    if (kt + 1 < NT) STAGE(An, Bn, kt + 1);
    bf16x8 af[4][2], bfr[4][2];
    #pragma unroll
    for (int i = 0; i < 4; ++i) {
      const int arow = wm * 64 + i * 16 + lm;
      const int brow = wn * 64 + i * 16 + lm;
      #pragma unroll
      for (int ks = 0; ks < 2; ++ks) {
        af[i][ks]  = *(const bf16x8*)&Ac[arow * BK + (((ks * 4 + kg) ^ (arow & 7)) << 3)];
        bfr[i][ks] = *(const bf16x8*)&Bc[brow * BK + (((ks * 4 + kg) ^ (brow & 7)) << 3)];
      }
    }
    #pragma unroll
    for (int ks = 0; ks < 2; ++ks)
      #pragma unroll
      for (int i = 0; i < 4; ++i)
        #pragma unroll
        for (int j = 0; j < 4; ++j)
          acc[i][j] = __builtin_amdgcn_mfma_f32_16x16x32_bf16(af[i][ks], bfr[j][ks], acc[i][j], 0, 0, 0);
    __syncthreads();
    unsigned short* tp;
    tp = Ac; Ac = An; An = tp;
    tp = Bc; Bc = Bn; Bn = tp;
  }

  #pragma unroll
  for (int i = 0; i < 4; ++i) {
    #pragma unroll
    for (int rr = 0; rr < 4; ++rr) {
      const int mloc = wm * 64 + i * 16 + kg * 4 + rr;
      const float s0 = st_s[mloc][0], s1 = st_s[mloc][1], s2 = st_s[mloc][2];
      float* orow = out + (size_t)(m0 + mloc) * V_ + n0;
      #pragma unroll
      for (int j = 0; j < 4; ++j) {
        const int nloc = wn * 64 + j * 16 + lm;
        if (n0 + nloc < V_) {
          const float corr = 0.1f * (s0 * wm_s[nloc][0] + s1 * wm_s[nloc][1] + s2 * wm_s[nloc][2]);
          orow[nloc] = acc[i][j][rr] + corr;
        }
      }
    }
  }
}

// ---------------- Last-resort (tiny ws): f32 reg-staged GEMM (R1)
__global__ __launch_bounds__(256) void ttu_gemm_kernel(
    const float* __restrict__ Ag, const float* __restrict__ Bg,
    const float* __restrict__ states, const float* __restrict__ Wmod,
    float* __restrict__ out)
{
  __shared__ unsigned short A_s[128][40];
  __shared__ unsigned short B_s[128][40];
  __shared__ float st_s[128][3];
  __shared__ float wm_s[128][3];

  const int t   = threadIdx.x;
  const int bid = blockIdx.x;
  const int mb  = bid & 15;
  const int nb  = bid >> 4;
  const int m0  = mb * 128;
  const int n0  = nb * 128;

  if (t < 128) {
    const int m = m0 + t;
    const int b = m >> 10;
    const int s = m & (S_ - 1);
    const float* st = states + (size_t)(s * B_ + b) * 3;
    st_s[t][0] = st[0]; st_s[t][1] = st[1]; st_s[t][2] = st[2];
  } else {
    const int tt = t - 128;
    const int n  = n0 + tt;
    const bool ok = n < V_;
    wm_s[tt][0] = ok ? Wmod[n * 3 + 0] : 0.f;
    wm_s[tt][1] = ok ? Wmod[n * 3 + 1] : 0.f;
    wm_s[tt][2] = ok ? Wmod[n * 3 + 2] : 0.f;
  }

  const int r   = t >> 1;
  const int seg = t & 1;
  const float* arow = Ag + (size_t)(m0 + r) * H_ + seg * 16;
  const int  vrow = n0 + r;
  const bool bok  = vrow < V_;
  const float* brow = Bg + (size_t)(bok ? vrow : 0) * H_ + seg * 16;

  const int lane = t & 63;
  const int wid  = t >> 6;
  const int wm   = wid >> 1;
  const int wn   = wid & 1;
  const int lm   = lane & 15;
  const int kg   = lane >> 4;

  f32x4 acc[4][4];
  #pragma unroll
  for (int i = 0; i < 4; ++i)
    #pragma unroll
    for (int j = 0; j < 4; ++j)
      acc[i][j] = (f32x4){0.f, 0.f, 0.f, 0.f};

  for (int kt = 0; kt < H_ / 32; ++kt) {
    const int k0 = kt * 32;
    const float4 av0 = *(const float4*)(arow + k0 + 0);
    const float4 av1 = *(const float4*)(arow + k0 + 4);
    const float4 av2 = *(const float4*)(arow + k0 + 8);
    const float4 av3 = *(const float4*)(arow + k0 + 12);
    float4 bv0 = {0,0,0,0}, bv1 = {0,0,0,0}, bv2 = {0,0,0,0}, bv3 = {0,0,0,0};
    if (bok) {
      bv0 = *(const float4*)(brow + k0 + 0);
      bv1 = *(const float4*)(brow + k0 + 4);
      bv2 = *(const float4*)(brow + k0 + 8);
      bv3 = *(const float4*)(brow + k0 + 12);
    }
    __syncthreads();
    #define CVT4(v) (bf16x4){(short)f2bf((v).x), (short)f2bf((v).y), (short)f2bf((v).z), (short)f2bf((v).w)}
    *(bf16x4*)&A_s[r][seg * 16 + 0]  = CVT4(av0);
    *(bf16x4*)&A_s[r][seg * 16 + 4]  = CVT4(av1);
    *(bf16x4*)&A_s[r][seg * 16 + 8]  = CVT4(av2);
    *(bf16x4*)&A_s[r][seg * 16 + 12] = CVT4(av3);
    *(bf16x4*)&B_s[r][seg * 16 + 0]  = CVT4(bv0);
    *(bf16x4*)&B_s[r][seg * 16 + 4]  = CVT4(bv1);
    *(bf16x4*)&B_s[r][seg * 16 + 8]  = CVT4(bv2);
    *(bf16x4*)&B_s[r][seg * 16 + 12] = CVT4(bv3);
    #undef CVT4
    __syncthreads();
    bf16x8 af[4], bf[4];
    #pragma unroll
    for (int i = 0; i < 4; ++i) {
      af[i] = *(const bf16x8*)&A_s[wm * 64 + i * 16 + lm][kg * 8];
      bf[i] = *(const bf16x8*)&B_s[wn * 64 + i * 16 + lm][kg * 8];
    }
    #pragma unroll
    for (int i = 0; i < 4; ++i)
      #pragma unroll
      for (int j = 0; j < 4; ++j)
        acc[i][j] = __builtin_amdgcn_mfma_f32_16x16x32_bf16(af[i], bf[j], acc[i][j], 0, 0, 0);
  }

  #pragma unroll
  for (int i = 0; i < 4; ++i) {
    #pragma unroll
    for (int rr = 0; rr < 4; ++rr) {
      const int mloc = wm * 64 + i * 16 + kg * 4 + rr;
      const float s0 = st_s[mloc][0], s1 = st_s[mloc][1], s2 = st_s[mloc][2];
      float* orow = out + (size_t)(m0 + mloc) * V_ + n0;
      #pragma unroll
      for (int j = 0; j < 4; ++j) {
        const int nloc = wn * 64 + j * 16 + lm;
        if (n0 + nloc < V_) {
          const float corr = 0.1f * (s0 * wm_s[nloc][0] + s1 * wm_s[nloc][1] + s2 * wm_s[nloc][2]);
          orow[nloc] = acc[i][j][rr] + corr;
        }
      }
    }
  }
}

} // namespace

extern "C" void kernel_launch(void* const* d_in, const int* in_sizes, int n_in,
                              void* d_out, int out_size, void* d_ws, size_t ws_size,
                              hipStream_t stream) {
  const float* hidden     = (const float*)d_in[0];
  const float* ttu_state  = (const float*)d_in[1];
  const float* W_imp      = (const float*)d_in[2];
  const float* b_imp      = (const float*)d_in[3];
  const float* W_lm       = (const float*)d_in[4];
  const float* W_mod      = (const float*)d_in[5];
  const float* ttu_params = (const float*)d_in[6];
  float* out = (float*)d_out;

  float* imp    = (float*)d_ws;          // 2048 f32
  float* states = imp + S_ * B_;         // 6144 f32  (32 KB total)
  float* final_out = out + (size_t)B_ * S_ * V_;

  const size_t need256 = 32768 + (size_t)M_ * H_ * 2 + (size_t)VP2_ * H_ * 2;
  const size_t need128 = 32768 + (size_t)M_ * H_ * 2 + (size_t)VP1_ * H_ * 2;

  if (ws_size >= need256) {
    unsigned short* hid_bf = (unsigned short*)((char*)d_ws + 32768);
    unsigned short* wlm_bf = hid_bf + (size_t)M_ * H_;
    cvt_hidden_impulse_kernel<<<M_, 256, 0, stream>>>(hidden, W_imp, b_imp, hid_bf, imp);
    cvt_wlm_scan_kernel<<<2049, 256, 0, stream>>>(W_lm, wlm_bf,
                                                  (long)V_ * H_, (long)VP2_ * H_,
                                                  imp, ttu_state, ttu_params,
                                                  states, final_out);
    const int grid = (VP2_ / 256) * (M_ / 256);   // 197*8 = 1576
    ttu_gemm_bf16_256p4_kernel<<<grid, 512, 0, stream>>>(hid_bf, wlm_bf, states, W_mod, out);
  } else if (ws_size >= need128) {
    unsigned short* hid_bf = (unsigned short*)((char*)d_ws + 32768);
    unsigned short* wlm_bf = hid_bf + (size_t)M_ * H_;
    cvt_hidden_impulse_kernel<<<M_, 256, 0, stream>>>(hidden, W_imp, b_imp, hid_bf, imp);
    ttu_scan_kernel<<<1, 64, 0, stream>>>(imp, ttu_state, ttu_params, states, final_out);
    cvt_bf16_kernel<<<4096, 256, 0, stream>>>(W_lm, wlm_bf, (long)V_ * H_, (long)VP1_ * H_);
    const int grid = (VP1_ / 128) * (M_ / 128);   // 393*16 = 6288
    ttu_gemm_bf16_db_kernel<<<grid, 256, 0, stream>>>(hid_bf, wlm_bf, states, W_mod, out);
  } else {
    cvt_hidden_impulse_kernel<<<M_, 256, 0, stream>>>(hidden, W_imp, b_imp,
                                                      (unsigned short*)d_ws, imp);
    ttu_scan_kernel<<<1, 64, 0, stream>>>(imp, ttu_state, ttu_params, states, final_out);
    const int grid = ((V_ + 127) / 128) * (M_ / 128);
    ttu_gemm_kernel<<<grid, 256, 0, stream>>>(hidden, W_lm, states, W_mod, out);
  }
}

// Round 8
// 527.416 us; speedup vs baseline: 1.1376x; 1.1376x over previous
//
#include <hip/hip_runtime.h>
#include <hip/hip_bf16.h>

typedef float  f32x4  __attribute__((ext_vector_type(4)));
typedef short  bf16x8 __attribute__((ext_vector_type(8)));
typedef short  bf16x4 __attribute__((ext_vector_type(4)));

typedef const void __attribute__((address_space(1))) gv_t;
typedef void __attribute__((address_space(3))) sv_t;

namespace {

constexpr int B_ = 2;
constexpr int S_ = 1024;
constexpr int H_ = 1024;
constexpr int V_ = 50257;
constexpr int M_ = B_ * S_;          // 2048
constexpr int VP1_ = 50304;          // 393*128, zero-padded W_lm rows
constexpr float DT_ = 0.1f;
constexpr float THRESH_ = 10.0f;

constexpr int BK = 64;
constexpr int NT = H_ / BK;          // 16 K-tiles

__device__ __forceinline__ unsigned short f2bf(float f) {
  union { float f; unsigned u; } x;
  x.f = f;
  x.u += 0x7FFFu + ((x.u >> 16) & 1u);   // RNE (no NaNs in this problem)
  return (unsigned short)(x.u >> 16);
}

// ---------------- Kernel 1: hidden f32 -> bf16, fused with impulse dot
__global__ void cvt_hidden_impulse_kernel(const float* __restrict__ hidden,
                                          const float* __restrict__ W_imp,
                                          const float* __restrict__ b_imp,
                                          unsigned short* __restrict__ hid_bf,
                                          float* __restrict__ imp) {
  const int m = blockIdx.x;
  const int t = threadIdx.x;
  const float4 hv = reinterpret_cast<const float4*>(hidden + (size_t)m * H_)[t];
  const float4 wv = reinterpret_cast<const float4*>(W_imp)[t];   // row 0
  bf16x4 o;
  o[0] = (short)f2bf(hv.x); o[1] = (short)f2bf(hv.y);
  o[2] = (short)f2bf(hv.z); o[3] = (short)f2bf(hv.w);
  *(bf16x4*)(hid_bf + (size_t)m * H_ + t * 4) = o;
  float p = hv.x * wv.x + hv.y * wv.y + hv.z * wv.z + hv.w * wv.w;
  #pragma unroll
  for (int off = 32; off; off >>= 1) p += __shfl_down(p, off);
  __shared__ float partial[4];
  if ((t & 63) == 0) partial[t >> 6] = p;
  __syncthreads();
  if (t == 0) {
    const float v = partial[0] + partial[1] + partial[2] + partial[3] + b_imp[0];
    const int b = m >> 10;
    const int s = m & (S_ - 1);
    imp[s * B_ + b] = v;
  }
}

// ---------------- scan body
__device__ __forceinline__ void scan_body(const float* __restrict__ imp_s,
                                          const float* __restrict__ ttu_state,
                                          const float* __restrict__ ttu_params,
                                          float* __restrict__ states,
                                          float* __restrict__ final_out, int t) {
  if (t < B_) {
    const float gamma   = ttu_params[0];
    const float alpha_c = ttu_params[1];
    const float beta_c  = ttu_params[2];
    const float delta   = ttu_params[3];
    const float alpha_d = ttu_params[4];
    const float epsilon = ttu_params[5];
    const float alpha_m = ttu_params[6];
    float c = ttu_state[t * 3 + 0];
    float d = ttu_state[t * 3 + 1];
    float m = ttu_state[t * 3 + 2];
    for (int s = 0; s < S_; ++s) {
      const float ii = imp_s[s * B_ + t];
      const float dc = gamma * ii - alpha_c * c - beta_c * c * d;
      const float dd = delta * c * c - alpha_d * d;
      const float dm = epsilon * d - alpha_m * m;
      c = c + DT_ * dc;
      float nd = d + DT_ * dd;
      m = m + DT_ * dm;
      nd = (fabsf(nd) > THRESH_ ? 0.5f : 1.0f) * nd;
      d = nd;
      float* st = states + (size_t)(s * B_ + t) * 3;
      st[0] = c; st[1] = d; st[2] = m;
    }
    final_out[t * 3 + 0] = c;
    final_out[t * 3 + 1] = d;
    final_out[t * 3 + 2] = m;
  }
}

__global__ void ttu_scan_kernel(const float* __restrict__ imp,
                                const float* __restrict__ ttu_state,
                                const float* __restrict__ ttu_params,
                                float* __restrict__ states,
                                float* __restrict__ final_out) {
  __shared__ float imp_s[S_ * B_];
  const int t = threadIdx.x;  // 64
  for (int i = t; i < S_ * B_; i += 64) imp_s[i] = imp[i];
  __syncthreads();
  scan_body(imp_s, ttu_state, ttu_params, states, final_out, t);
}

// ---------------- Kernel 2.5: W_lm f32 -> bf16 + fused scan (last block)
__global__ void cvt_wlm_scan_kernel(const float* __restrict__ src,
                                    unsigned short* __restrict__ dst,
                                    long n_src, long n_dst,
                                    const float* __restrict__ imp,
                                    const float* __restrict__ ttu_state,
                                    const float* __restrict__ ttu_params,
                                    float* __restrict__ states,
                                    float* __restrict__ final_out) {
  __shared__ float imp_s[S_ * B_];
  const int t = threadIdx.x;   // 256
  if (blockIdx.x == gridDim.x - 1) {
    for (int i = t; i < S_ * B_; i += 256) imp_s[i] = imp[i];
    __syncthreads();
    scan_body(imp_s, ttu_state, ttu_params, states, final_out, t);
    return;
  }
  const long stride = (long)(gridDim.x - 1) * blockDim.x * 8;
  for (long i = ((long)blockIdx.x * blockDim.x + t) * 8; i < n_dst; i += stride) {
    bf16x8 v;
    if (i < n_src) {     // n_src multiple of 8; vectors never straddle
      const float4 a = *(const float4*)(src + i);
      const float4 b = *(const float4*)(src + i + 4);
      v[0] = (short)f2bf(a.x); v[1] = (short)f2bf(a.y);
      v[2] = (short)f2bf(a.z); v[3] = (short)f2bf(a.w);
      v[4] = (short)f2bf(b.x); v[5] = (short)f2bf(b.y);
      v[6] = (short)f2bf(b.z); v[7] = (short)f2bf(b.w);
    } else {
      v = (bf16x8){0, 0, 0, 0, 0, 0, 0, 0};
    }
    *(bf16x8*)(dst + i) = v;
  }
}

// ---------------- Kernel 3 (fast): 128x128, 2-buffer free-running counted vmcnt
// = R3's proven skeleton (64 KB LDS -> 2 blocks/CU, inter-block overlap) with
// R5's proven counted-vmcnt (loads stay in flight across barriers).
// Per tile kt (race-free ledger):
//   1. s_barrier: all waves done reading buf[nxt] (tile kt-1) -> WAR-safe.
//   2. STAGE(nxt, kt+1): 8 gload_lds/wave.
//   3. s_waitcnt vmcnt(8): per-wave FIFO drains exactly tile kt's 8 loads
//      (kt+1's 8 remain in flight). Last tile: vmcnt(0).
//   4. s_barrier: publish -> every wave's kt loads landed.
//   5. Frag reads + 32 MFMA free-running (compiler lgkmcnt; no pins).
// LDS chunk-XOR swizzle as R2-R7 (BANK_CONFLICT==0 verified).
__global__ __launch_bounds__(256, 2) void ttu_gemm_bf16_cnt_kernel(
    const unsigned short* __restrict__ Ab,   // hidden bf16 [M_][H_]
    const unsigned short* __restrict__ Bb,   // W_lm bf16 [VP1_][H_]
    const float* __restrict__ states,
    const float* __restrict__ Wmod,
    float* __restrict__ out)
{
  __shared__ unsigned short AB_s[2][2][128 * BK];   // 64 KiB
  __shared__ float st_s[128][3];
  __shared__ float wm_s[128][3];

  const int t = threadIdx.x;
  const int cpx = gridDim.x >> 3;              // 786; grid 6288 % 8 == 0
  const int bid = (blockIdx.x & 7) * cpx + (blockIdx.x >> 3);
  const int mb = bid & 15;                     // M fastest: share B-panel
  const int nb = bid >> 4;
  const int m0 = mb * 128;
  const int n0 = nb * 128;

  if (t < 128) {
    const int m = m0 + t;
    const int b = m >> 10;
    const int s = m & (S_ - 1);
    const float* st = states + (size_t)(s * B_ + b) * 3;
    st_s[t][0] = st[0]; st_s[t][1] = st[1]; st_s[t][2] = st[2];
  } else {
    const int tt = t - 128;
    const int n = n0 + tt;
    const bool ok = n < V_;
    wm_s[tt][0] = ok ? Wmod[n * 3 + 0] : 0.f;
    wm_s[tt][1] = ok ? Wmod[n * 3 + 1] : 0.f;
    wm_s[tt][2] = ok ? Wmod[n * 3 + 2] : 0.f;
  }

  const int lane = t & 63;
  const int wid  = t >> 6;             // 4 waves (2x2)
  const int lr   = lane >> 3;          // staging sub-row 0..7
  const int ch   = lane & 7;           // staging 16B chunk 0..7
  const int wm   = wid >> 1;
  const int wn   = wid & 1;
  const int lm   = lane & 15;
  const int kg   = lane >> 4;

  const unsigned short* Abase = Ab + (size_t)m0 * H_;
  const unsigned short* Bbase = Bb + (size_t)n0 * H_;
  const int r0 = wid * 32;

  auto STAGE = [&](unsigned short* As, unsigned short* Bs, int kt) {
    const int k0 = kt * BK;
    #pragma unroll
    for (int ins = 0; ins < 4; ++ins) {
      const int lrow = r0 + ins * 8 + lr;
      const int sch  = ch ^ (lrow & 7);
      __builtin_amdgcn_global_load_lds(
          (gv_t*)(Abase + (size_t)lrow * H_ + k0 + sch * 8),
          (sv_t*)(As + (r0 + ins * 8) * BK), 16, 0, 0);
    }
    #pragma unroll
    for (int ins = 0; ins < 4; ++ins) {
      const int lrow = r0 + ins * 8 + lr;
      const int sch  = ch ^ (lrow & 7);
      __builtin_amdgcn_global_load_lds(
          (gv_t*)(Bbase + (size_t)lrow * H_ + k0 + sch * 8),
          (sv_t*)(Bs + (r0 + ins * 8) * BK), 16, 0, 0);
    }
  };

  f32x4 acc[4][4];
  #pragma unroll
  for (int i = 0; i < 4; ++i)
    #pragma unroll
    for (int j = 0; j < 4; ++j)
      acc[i][j] = (f32x4){0.f, 0.f, 0.f, 0.f};

  unsigned short* Ac = &AB_s[0][0][0];
  unsigned short* Bc = &AB_s[0][1][0];
  unsigned short* An = &AB_s[1][0][0];
  unsigned short* Bn = &AB_s[1][1][0];

  STAGE(Ac, Bc, 0);   // tile 0 in flight; drained by first in-loop vmcnt

  for (int kt = 0; kt < NT; ++kt) {
    asm volatile("s_barrier" ::: "memory");        // WAR: buf[nxt] reads done
    if (kt + 1 < NT) {
      STAGE(An, Bn, kt + 1);
      asm volatile("s_waitcnt vmcnt(8)" ::: "memory");   // drain tile kt's 8
    } else {
      asm volatile("s_waitcnt vmcnt(0)" ::: "memory");
    }
    asm volatile("s_barrier" ::: "memory");        // publish tile kt

    bf16x8 af[4][2], bfr[4][2];
    #pragma unroll
    for (int i = 0; i < 4; ++i) {
      const int arow = wm * 64 + i * 16 + lm;
      const int brow = wn * 64 + i * 16 + lm;
      #pragma unroll
      for (int ks = 0; ks < 2; ++ks) {
        af[i][ks]  = *(const bf16x8*)&Ac[arow * BK + (((ks * 4 + kg) ^ (arow & 7)) << 3)];
        bfr[i][ks] = *(const bf16x8*)&Bc[brow * BK + (((ks * 4 + kg) ^ (brow & 7)) << 3)];
      }
    }
    #pragma unroll
    for (int ks = 0; ks < 2; ++ks)
      #pragma unroll
      for (int i = 0; i < 4; ++i)
        #pragma unroll
        for (int j = 0; j < 4; ++j)
          acc[i][j] = __builtin_amdgcn_mfma_f32_16x16x32_bf16(af[i][ks], bfr[j][ks], acc[i][j], 0, 0, 0);

    unsigned short* tp;
    tp = Ac; Ac = An; An = tp;
    tp = Bc; Bc = Bn; Bn = tp;
  }

  // Epilogue: += 0.1 * states . W_mod^T; non-temporal streamed stores
  #pragma unroll
  for (int i = 0; i < 4; ++i) {
    #pragma unroll
    for (int rr = 0; rr < 4; ++rr) {
      const int mloc = wm * 64 + i * 16 + kg * 4 + rr;
      const float s0 = st_s[mloc][0], s1 = st_s[mloc][1], s2 = st_s[mloc][2];
      float* orow = out + (size_t)(m0 + mloc) * V_ + n0;
      #pragma unroll
      for (int j = 0; j < 4; ++j) {
        const int nloc = wn * 64 + j * 16 + lm;
        if (n0 + nloc < V_) {
          const float corr = 0.1f * (s0 * wm_s[nloc][0] + s1 * wm_s[nloc][1] + s2 * wm_s[nloc][2]);
          __builtin_nontemporal_store(acc[i][j][rr] + corr, &orow[nloc]);
        }
      }
    }
  }
}

// ---------------- Last-resort (tiny ws): f32 reg-staged GEMM (R1)
__global__ __launch_bounds__(256) void ttu_gemm_kernel(
    const float* __restrict__ Ag, const float* __restrict__ Bg,
    const float* __restrict__ states, const float* __restrict__ Wmod,
    float* __restrict__ out)
{
  __shared__ unsigned short A_s[128][40];
  __shared__ unsigned short B_s[128][40];
  __shared__ float st_s[128][3];
  __shared__ float wm_s[128][3];

  const int t   = threadIdx.x;
  const int bid = blockIdx.x;
  const int mb  = bid & 15;
  const int nb  = bid >> 4;
  const int m0  = mb * 128;
  const int n0  = nb * 128;

  if (t < 128) {
    const int m = m0 + t;
    const int b = m >> 10;
    const int s = m & (S_ - 1);
    const float* st = states + (size_t)(s * B_ + b) * 3;
    st_s[t][0] = st[0]; st_s[t][1] = st[1]; st_s[t][2] = st[2];
  } else {
    const int tt = t - 128;
    const int n  = n0 + tt;
    const bool ok = n < V_;
    wm_s[tt][0] = ok ? Wmod[n * 3 + 0] : 0.f;
    wm_s[tt][1] = ok ? Wmod[n * 3 + 1] : 0.f;
    wm_s[tt][2] = ok ? Wmod[n * 3 + 2] : 0.f;
  }

  const int r   = t >> 1;
  const int seg = t & 1;
  const float* arow = Ag + (size_t)(m0 + r) * H_ + seg * 16;
  const int  vrow = n0 + r;
  const bool bok  = vrow < V_;
  const float* brow = Bg + (size_t)(bok ? vrow : 0) * H_ + seg * 16;

  const int lane = t & 63;
  const int wid  = t >> 6;
  const int wm   = wid >> 1;
  const int wn   = wid & 1;
  const int lm   = lane & 15;
  const int kg   = lane >> 4;

  f32x4 acc[4][4];
  #pragma unroll
  for (int i = 0; i < 4; ++i)
    #pragma unroll
    for (int j = 0; j < 4; ++j)
      acc[i][j] = (f32x4){0.f, 0.f, 0.f, 0.f};

  for (int kt = 0; kt < H_ / 32; ++kt) {
    const int k0 = kt * 32;
    const float4 av0 = *(const float4*)(arow + k0 + 0);
    const float4 av1 = *(const float4*)(arow + k0 + 4);
    const float4 av2 = *(const float4*)(arow + k0 + 8);
    const float4 av3 = *(const float4*)(arow + k0 + 12);
    float4 bv0 = {0,0,0,0}, bv1 = {0,0,0,0}, bv2 = {0,0,0,0}, bv3 = {0,0,0,0};
    if (bok) {
      bv0 = *(const float4*)(brow + k0 + 0);
      bv1 = *(const float4*)(brow + k0 + 4);
      bv2 = *(const float4*)(brow + k0 + 8);
      bv3 = *(const float4*)(brow + k0 + 12);
    }
    __syncthreads();
    #define CVT4(v) (bf16x4){(short)f2bf((v).x), (short)f2bf((v).y), (short)f2bf((v).z), (short)f2bf((v).w)}
    *(bf16x4*)&A_s[r][seg * 16 + 0]  = CVT4(av0);
    *(bf16x4*)&A_s[r][seg * 16 + 4]  = CVT4(av1);
    *(bf16x4*)&A_s[r][seg * 16 + 8]  = CVT4(av2);
    *(bf16x4*)&A_s[r][seg * 16 + 12] = CVT4(av3);
    *(bf16x4*)&B_s[r][seg * 16 + 0]  = CVT4(bv0);
    *(bf16x4*)&B_s[r][seg * 16 + 4]  = CVT4(bv1);
    *(bf16x4*)&B_s[r][seg * 16 + 8]  = CVT4(bv2);
    *(bf16x4*)&B_s[r][seg * 16 + 12] = CVT4(bv3);
    #undef CVT4
    __syncthreads();
    bf16x8 af[4], bf[4];
    #pragma unroll
    for (int i = 0; i < 4; ++i) {
      af[i] = *(const bf16x8*)&A_s[wm * 64 + i * 16 + lm][kg * 8];
      bf[i] = *(const bf16x8*)&B_s[wn * 64 + i * 16 + lm][kg * 8];
    }
    #pragma unroll
    for (int i = 0; i < 4; ++i)
      #pragma unroll
      for (int j = 0; j < 4; ++j)
        acc[i][j] = __builtin_amdgcn_mfma_f32_16x16x32_bf16(af[i], bf[j], acc[i][j], 0, 0, 0);
  }

  #pragma unroll
  for (int i = 0; i < 4; ++i) {
    #pragma unroll
    for (int rr = 0; rr < 4; ++rr) {
      const int mloc = wm * 64 + i * 16 + kg * 4 + rr;
      const float s0 = st_s[mloc][0], s1 = st_s[mloc][1], s2 = st_s[mloc][2];
      float* orow = out + (size_t)(m0 + mloc) * V_ + n0;
      #pragma unroll
      for (int j = 0; j < 4; ++j) {
        const int nloc = wn * 64 + j * 16 + lm;
        if (n0 + nloc < V_) {
          const float corr = 0.1f * (s0 * wm_s[nloc][0] + s1 * wm_s[nloc][1] + s2 * wm_s[nloc][2]);
          orow[nloc] = acc[i][j][rr] + corr;
        }
      }
    }
  }
}

} // namespace

extern "C" void kernel_launch(void* const* d_in, const int* in_sizes, int n_in,
                              void* d_out, int out_size, void* d_ws, size_t ws_size,
                              hipStream_t stream) {
  const float* hidden     = (const float*)d_in[0];
  const float* ttu_state  = (const float*)d_in[1];
  const float* W_imp      = (const float*)d_in[2];
  const float* b_imp      = (const float*)d_in[3];
  const float* W_lm       = (const float*)d_in[4];
  const float* W_mod      = (const float*)d_in[5];
  const float* ttu_params = (const float*)d_in[6];
  float* out = (float*)d_out;

  float* imp    = (float*)d_ws;          // 2048 f32
  float* states = imp + S_ * B_;         // 6144 f32  (32 KB total)
  float* final_out = out + (size_t)B_ * S_ * V_;

  const size_t need = 32768 + (size_t)M_ * H_ * 2 + (size_t)VP1_ * H_ * 2;

  if (ws_size >= need) {
    unsigned short* hid_bf = (unsigned short*)((char*)d_ws + 32768);
    unsigned short* wlm_bf = hid_bf + (size_t)M_ * H_;
    cvt_hidden_impulse_kernel<<<M_, 256, 0, stream>>>(hidden, W_imp, b_imp, hid_bf, imp);
    cvt_wlm_scan_kernel<<<2049, 256, 0, stream>>>(W_lm, wlm_bf,
                                                  (long)V_ * H_, (long)VP1_ * H_,
                                                  imp, ttu_state, ttu_params,
                                                  states, final_out);
    const int grid = (VP1_ / 128) * (M_ / 128);   // 393*16 = 6288
    ttu_gemm_bf16_cnt_kernel<<<grid, 256, 0, stream>>>(hid_bf, wlm_bf, states, W_mod, out);
  } else {
    cvt_hidden_impulse_kernel<<<M_, 256, 0, stream>>>(hidden, W_imp, b_imp,
                                                      (unsigned short*)d_ws, imp);
    ttu_scan_kernel<<<1, 64, 0, stream>>>(imp, ttu_state, ttu_params, states, final_out);
    const int grid = ((V_ + 127) / 128) * (M_ / 128);
    ttu_gemm_kernel<<<grid, 256, 0, stream>>>(hidden, W_lm, states, W_mod, out);
  }
}

// Round 9
// 487.861 us; speedup vs baseline: 1.2298x; 1.0811x over previous
//
#include <hip/hip_runtime.h>
#include <hip/hip_bf16.h>

typedef float  f32x4  __attribute__((ext_vector_type(4)));
typedef short  bf16x8 __attribute__((ext_vector_type(8)));
typedef short  bf16x4 __attribute__((ext_vector_type(4)));

typedef const void __attribute__((address_space(1))) gv_t;
typedef void __attribute__((address_space(3))) sv_t;

namespace {

constexpr int B_ = 2;
constexpr int S_ = 1024;
constexpr int H_ = 1024;
constexpr int V_ = 50257;
constexpr int M_ = B_ * S_;          // 2048
constexpr int VP1_ = 50304;          // 393*128, zero-padded W_lm rows
constexpr float DT_ = 0.1f;
constexpr float THRESH_ = 10.0f;

constexpr int BK3 = 32;              // fast kernel K-tile
constexpr int NT3 = H_ / BK3;        // 32

__device__ __forceinline__ unsigned short f2bf(float f) {
  union { float f; unsigned u; } x;
  x.f = f;
  x.u += 0x7FFFu + ((x.u >> 16) & 1u);   // RNE (no NaNs in this problem)
  return (unsigned short)(x.u >> 16);
}

// ---------------- Kernel 1: hidden f32 -> bf16, fused with impulse dot
__global__ void cvt_hidden_impulse_kernel(const float* __restrict__ hidden,
                                          const float* __restrict__ W_imp,
                                          const float* __restrict__ b_imp,
                                          unsigned short* __restrict__ hid_bf,
                                          float* __restrict__ imp) {
  const int m = blockIdx.x;
  const int t = threadIdx.x;
  const float4 hv = reinterpret_cast<const float4*>(hidden + (size_t)m * H_)[t];
  const float4 wv = reinterpret_cast<const float4*>(W_imp)[t];   // row 0
  bf16x4 o;
  o[0] = (short)f2bf(hv.x); o[1] = (short)f2bf(hv.y);
  o[2] = (short)f2bf(hv.z); o[3] = (short)f2bf(hv.w);
  *(bf16x4*)(hid_bf + (size_t)m * H_ + t * 4) = o;
  float p = hv.x * wv.x + hv.y * wv.y + hv.z * wv.z + hv.w * wv.w;
  #pragma unroll
  for (int off = 32; off; off >>= 1) p += __shfl_down(p, off);
  __shared__ float partial[4];
  if ((t & 63) == 0) partial[t >> 6] = p;
  __syncthreads();
  if (t == 0) {
    const float v = partial[0] + partial[1] + partial[2] + partial[3] + b_imp[0];
    const int b = m >> 10;
    const int s = m & (S_ - 1);
    imp[s * B_ + b] = v;
  }
}

// ---------------- scan body
__device__ __forceinline__ void scan_body(const float* __restrict__ imp_s,
                                          const float* __restrict__ ttu_state,
                                          const float* __restrict__ ttu_params,
                                          float* __restrict__ states,
                                          float* __restrict__ final_out, int t) {
  if (t < B_) {
    const float gamma   = ttu_params[0];
    const float alpha_c = ttu_params[1];
    const float beta_c  = ttu_params[2];
    const float delta   = ttu_params[3];
    const float alpha_d = ttu_params[4];
    const float epsilon = ttu_params[5];
    const float alpha_m = ttu_params[6];
    float c = ttu_state[t * 3 + 0];
    float d = ttu_state[t * 3 + 1];
    float m = ttu_state[t * 3 + 2];
    for (int s = 0; s < S_; ++s) {
      const float ii = imp_s[s * B_ + t];
      const float dc = gamma * ii - alpha_c * c - beta_c * c * d;
      const float dd = delta * c * c - alpha_d * d;
      const float dm = epsilon * d - alpha_m * m;
      c = c + DT_ * dc;
      float nd = d + DT_ * dd;
      m = m + DT_ * dm;
      nd = (fabsf(nd) > THRESH_ ? 0.5f : 1.0f) * nd;
      d = nd;
      float* st = states + (size_t)(s * B_ + t) * 3;
      st[0] = c; st[1] = d; st[2] = m;
    }
    final_out[t * 3 + 0] = c;
    final_out[t * 3 + 1] = d;
    final_out[t * 3 + 2] = m;
  }
}

__global__ void ttu_scan_kernel(const float* __restrict__ imp,
                                const float* __restrict__ ttu_state,
                                const float* __restrict__ ttu_params,
                                float* __restrict__ states,
                                float* __restrict__ final_out) {
  __shared__ float imp_s[S_ * B_];
  const int t = threadIdx.x;  // 64
  for (int i = t; i < S_ * B_; i += 64) imp_s[i] = imp[i];
  __syncthreads();
  scan_body(imp_s, ttu_state, ttu_params, states, final_out, t);
}

// ---------------- Kernel 2.5: W_lm f32 -> bf16 + fused scan (last block)
__global__ void cvt_wlm_scan_kernel(const float* __restrict__ src,
                                    unsigned short* __restrict__ dst,
                                    long n_src, long n_dst,
                                    const float* __restrict__ imp,
                                    const float* __restrict__ ttu_state,
                                    const float* __restrict__ ttu_params,
                                    float* __restrict__ states,
                                    float* __restrict__ final_out) {
  __shared__ float imp_s[S_ * B_];
  const int t = threadIdx.x;   // 256
  if (blockIdx.x == gridDim.x - 1) {
    for (int i = t; i < S_ * B_; i += 256) imp_s[i] = imp[i];
    __syncthreads();
    scan_body(imp_s, ttu_state, ttu_params, states, final_out, t);
    return;
  }
  const long stride = (long)(gridDim.x - 1) * blockDim.x * 8;
  for (long i = ((long)blockIdx.x * blockDim.x + t) * 8; i < n_dst; i += stride) {
    bf16x8 v;
    if (i < n_src) {     // n_src multiple of 8; vectors never straddle
      const float4 a = *(const float4*)(src + i);
      const float4 b = *(const float4*)(src + i + 4);
      v[0] = (short)f2bf(a.x); v[1] = (short)f2bf(a.y);
      v[2] = (short)f2bf(a.z); v[3] = (short)f2bf(a.w);
      v[4] = (short)f2bf(b.x); v[5] = (short)f2bf(b.y);
      v[6] = (short)f2bf(b.z); v[7] = (short)f2bf(b.w);
    } else {
      v = (bf16x8){0, 0, 0, 0, 0, 0, 0, 0};
    }
    *(bf16x8*)(dst + i) = v;
  }
}

// ---------------- Kernel 3 (fast): 128x128, BK=32, 3-buffer, 3 blocks/CU
// The two measured levers combined: inter-block TLP (3 blocks/CU; R3 showed
// 2 blk/CU beats every 1-blk/CU 256^2 schedule) + counted vmcnt (R5).
// LDS = 3 bufs x (128+128) x 32 x 2B = 48 KB + 3 KB epilogue -> 160/51 = 3
// blocks/CU. Regs: ~88 VGPR + 64 acc = ~152 < 170 cap (launch_bounds 256,3).
// Per tile kt (race-free ledger):
//   1. s_barrier: all waves' reads of buf[(kt+2)%3] (tile kt-1) done -> WAR.
//   2. STAGE((kt+2)%3, kt+2): 4 gload_lds/wave, distance-2 prefetch.
//   3. s_waitcnt vmcnt(8): drains exactly tile kt's 4 (FIFO); kt+1/kt+2's 8
//      stay in flight. Tail: vmcnt(4), vmcnt(0).
//   4. s_barrier: publish tile kt.
//   5. Frag reads + 16 MFMA free-running (compiler lgkmcnt, no pins).
// LDS swizzle (BK=32, 4x16B chunks/row): LDS[r][c] = G[r][c ^ ((r>>1)&3)]
// via pre-swizzled source (linear dest, rule #21); read applies same XOR.
// Measured 0 bank conflicts with this geometry (R6).
__global__ __launch_bounds__(256, 3) void ttu_gemm_bf16_128x32_kernel(
    const unsigned short* __restrict__ Ab,   // hidden bf16 [M_][H_]
    const unsigned short* __restrict__ Bb,   // W_lm bf16 [VP1_][H_]
    const float* __restrict__ states,
    const float* __restrict__ Wmod,
    float* __restrict__ out)
{
  __shared__ unsigned short A_s[3][128 * BK3];   // 24 KiB
  __shared__ unsigned short B_s[3][128 * BK3];   // 24 KiB
  __shared__ float st_s[128][3];
  __shared__ float wm_s[128][3];

  const int t = threadIdx.x;
  const int cpx = gridDim.x >> 3;              // 786; grid 6288 % 8 == 0
  const int bid = (blockIdx.x & 7) * cpx + (blockIdx.x >> 3);
  const int mb = bid & 15;                     // M fastest: share B-panel
  const int nb = bid >> 4;
  const int m0 = mb * 128;
  const int n0 = nb * 128;

  if (t < 128) {
    const int m = m0 + t;
    const int b = m >> 10;
    const int s = m & (S_ - 1);
    const float* st = states + (size_t)(s * B_ + b) * 3;
    st_s[t][0] = st[0]; st_s[t][1] = st[1]; st_s[t][2] = st[2];
  } else {
    const int tt = t - 128;
    const int n = n0 + tt;
    const bool ok = n < V_;
    wm_s[tt][0] = ok ? Wmod[n * 3 + 0] : 0.f;
    wm_s[tt][1] = ok ? Wmod[n * 3 + 1] : 0.f;
    wm_s[tt][2] = ok ? Wmod[n * 3 + 2] : 0.f;
  }

  const int lane = t & 63;
  const int wid  = t >> 6;             // 4 waves (2x2)
  const int lr   = lane >> 2;          // staging sub-row 0..15
  const int ch   = lane & 3;           // staging 16B chunk 0..3
  const int wm   = wid >> 1;
  const int wn   = wid & 1;
  const int lm   = lane & 15;
  const int kg   = lane >> 4;          // k-chunk 0..3 (8 bf16)

  const unsigned short* Abase = Ab + (size_t)m0 * H_;
  const unsigned short* Bbase = Bb + (size_t)n0 * H_;

  // 4 gload_lds per wave per tile: A rows wid*32+{0,16}+lr, B same rows.
  auto STAGE = [&](int buf, int kt) {
    const int k0 = kt * BK3;
    #pragma unroll
    for (int h = 0; h < 2; ++h) {
      const unsigned short* gb = h ? Bbase : Abase;
      unsigned short* ls = h ? &B_s[buf][0] : &A_s[buf][0];
      #pragma unroll
      for (int n = 0; n < 2; ++n) {
        const int rbase = wid * 32 + n * 16;     // wave-uniform
        const int r  = rbase + lr;
        const int sc = ch ^ ((r >> 1) & 3);      // pre-swizzled source chunk
        __builtin_amdgcn_global_load_lds(
            (gv_t*)(gb + (size_t)r * H_ + k0 + sc * 8),
            (sv_t*)(ls + rbase * BK3), 16, 0, 0);
      }
    }
  };

  f32x4 acc[4][4];
  #pragma unroll
  for (int i = 0; i < 4; ++i)
    #pragma unroll
    for (int j = 0; j < 4; ++j)
      acc[i][j] = (f32x4){0.f, 0.f, 0.f, 0.f};

  // prologue: fill pipeline 2 deep
  STAGE(0, 0);
  STAGE(1, 1);

  int cur = 0, nxt2 = 2;
  for (int kt = 0; kt < NT3; ++kt) {
    asm volatile("s_barrier" ::: "memory");      // WAR: buf[nxt2] reads done
    if (kt + 2 < NT3) {
      STAGE(nxt2, kt + 2);
      asm volatile("s_waitcnt vmcnt(8)" ::: "memory");   // drain tile kt's 4
    } else if (kt + 1 < NT3) {
      asm volatile("s_waitcnt vmcnt(4)" ::: "memory");
    } else {
      asm volatile("s_waitcnt vmcnt(0)" ::: "memory");
    }
    asm volatile("s_barrier" ::: "memory");      // publish tile kt

    const unsigned short* As = &A_s[cur][0];
    const unsigned short* Bs = &B_s[cur][0];

    bf16x8 af[4], bfr[4];
    #pragma unroll
    for (int i = 0; i < 4; ++i) {
      const int arow = wm * 64 + i * 16 + lm;
      const int brow = wn * 64 + i * 16 + lm;
      af[i]  = *(const bf16x8*)&As[arow * BK3 + ((kg ^ ((arow >> 1) & 3)) << 3)];
      bfr[i] = *(const bf16x8*)&Bs[brow * BK3 + ((kg ^ ((brow >> 1) & 3)) << 3)];
    }
    #pragma unroll
    for (int i = 0; i < 4; ++i)
      #pragma unroll
      for (int j = 0; j < 4; ++j)
        acc[i][j] = __builtin_amdgcn_mfma_f32_16x16x32_bf16(af[i], bfr[j], acc[i][j], 0, 0, 0);

    cur = (cur == 2) ? 0 : cur + 1;
    nxt2 = (nxt2 == 2) ? 0 : nxt2 + 1;
  }

  // Epilogue: += 0.1 * states . W_mod^T; plain stores (NT stores regressed:
  // WRITE_SIZE 424->715 MB with odd-V row misalignment, R8)
  #pragma unroll
  for (int i = 0; i < 4; ++i) {
    #pragma unroll
    for (int rr = 0; rr < 4; ++rr) {
      const int mloc = wm * 64 + i * 16 + kg * 4 + rr;
      const float s0 = st_s[mloc][0], s1 = st_s[mloc][1], s2 = st_s[mloc][2];
      float* orow = out + (size_t)(m0 + mloc) * V_ + n0;
      #pragma unroll
      for (int j = 0; j < 4; ++j) {
        const int nloc = wn * 64 + j * 16 + lm;
        if (n0 + nloc < V_) {
          const float corr = 0.1f * (s0 * wm_s[nloc][0] + s1 * wm_s[nloc][1] + s2 * wm_s[nloc][2]);
          orow[nloc] = acc[i][j][rr] + corr;
        }
      }
    }
  }
}

// ---------------- Last-resort (tiny ws): f32 reg-staged GEMM (R1)
__global__ __launch_bounds__(256) void ttu_gemm_kernel(
    const float* __restrict__ Ag, const float* __restrict__ Bg,
    const float* __restrict__ states, const float* __restrict__ Wmod,
    float* __restrict__ out)
{
  __shared__ unsigned short A_s[128][40];
  __shared__ unsigned short B_s[128][40];
  __shared__ float st_s[128][3];
  __shared__ float wm_s[128][3];

  const int t   = threadIdx.x;
  const int bid = blockIdx.x;
  const int mb  = bid & 15;
  const int nb  = bid >> 4;
  const int m0  = mb * 128;
  const int n0  = nb * 128;

  if (t < 128) {
    const int m = m0 + t;
    const int b = m >> 10;
    const int s = m & (S_ - 1);
    const float* st = states + (size_t)(s * B_ + b) * 3;
    st_s[t][0] = st[0]; st_s[t][1] = st[1]; st_s[t][2] = st[2];
  } else {
    const int tt = t - 128;
    const int n  = n0 + tt;
    const bool ok = n < V_;
    wm_s[tt][0] = ok ? Wmod[n * 3 + 0] : 0.f;
    wm_s[tt][1] = ok ? Wmod[n * 3 + 1] : 0.f;
    wm_s[tt][2] = ok ? Wmod[n * 3 + 2] : 0.f;
  }

  const int r   = t >> 1;
  const int seg = t & 1;
  const float* arow = Ag + (size_t)(m0 + r) * H_ + seg * 16;
  const int  vrow = n0 + r;
  const bool bok  = vrow < V_;
  const float* brow = Bg + (size_t)(bok ? vrow : 0) * H_ + seg * 16;

  const int lane = t & 63;
  const int wid  = t >> 6;
  const int wm   = wid >> 1;
  const int wn   = wid & 1;
  const int lm   = lane & 15;
  const int kg   = lane >> 4;

  f32x4 acc[4][4];
  #pragma unroll
  for (int i = 0; i < 4; ++i)
    #pragma unroll
    for (int j = 0; j < 4; ++j)
      acc[i][j] = (f32x4){0.f, 0.f, 0.f, 0.f};

  for (int kt = 0; kt < H_ / 32; ++kt) {
    const int k0 = kt * 32;
    const float4 av0 = *(const float4*)(arow + k0 + 0);
    const float4 av1 = *(const float4*)(arow + k0 + 4);
    const float4 av2 = *(const float4*)(arow + k0 + 8);
    const float4 av3 = *(const float4*)(arow + k0 + 12);
    float4 bv0 = {0,0,0,0}, bv1 = {0,0,0,0}, bv2 = {0,0,0,0}, bv3 = {0,0,0,0};
    if (bok) {
      bv0 = *(const float4*)(brow + k0 + 0);
      bv1 = *(const float4*)(brow + k0 + 4);
      bv2 = *(const float4*)(brow + k0 + 8);
      bv3 = *(const float4*)(brow + k0 + 12);
    }
    __syncthreads();
    #define CVT4(v) (bf16x4){(short)f2bf((v).x), (short)f2bf((v).y), (short)f2bf((v).z), (short)f2bf((v).w)}
    *(bf16x4*)&A_s[r][seg * 16 + 0]  = CVT4(av0);
    *(bf16x4*)&A_s[r][seg * 16 + 4]  = CVT4(av1);
    *(bf16x4*)&A_s[r][seg * 16 + 8]  = CVT4(av2);
    *(bf16x4*)&A_s[r][seg * 16 + 12] = CVT4(av3);
    *(bf16x4*)&B_s[r][seg * 16 + 0]  = CVT4(bv0);
    *(bf16x4*)&B_s[r][seg * 16 + 4]  = CVT4(bv1);
    *(bf16x4*)&B_s[r][seg * 16 + 8]  = CVT4(bv2);
    *(bf16x4*)&B_s[r][seg * 16 + 12] = CVT4(bv3);
    #undef CVT4
    __syncthreads();
    bf16x8 af[4], bf[4];
    #pragma unroll
    for (int i = 0; i < 4; ++i) {
      af[i] = *(const bf16x8*)&A_s[wm * 64 + i * 16 + lm][kg * 8];
      bf[i] = *(const bf16x8*)&B_s[wn * 64 + i * 16 + lm][kg * 8];
    }
    #pragma unroll
    for (int i = 0; i < 4; ++i)
      #pragma unroll
      for (int j = 0; j < 4; ++j)
        acc[i][j] = __builtin_amdgcn_mfma_f32_16x16x32_bf16(af[i], bf[j], acc[i][j], 0, 0, 0);
  }

  #pragma unroll
  for (int i = 0; i < 4; ++i) {
    #pragma unroll
    for (int rr = 0; rr < 4; ++rr) {
      const int mloc = wm * 64 + i * 16 + kg * 4 + rr;
      const float s0 = st_s[mloc][0], s1 = st_s[mloc][1], s2 = st_s[mloc][2];
      float* orow = out + (size_t)(m0 + mloc) * V_ + n0;
      #pragma unroll
      for (int j = 0; j < 4; ++j) {
        const int nloc = wn * 64 + j * 16 + lm;
        if (n0 + nloc < V_) {
          const float corr = 0.1f * (s0 * wm_s[nloc][0] + s1 * wm_s[nloc][1] + s2 * wm_s[nloc][2]);
          orow[nloc] = acc[i][j][rr] + corr;
        }
      }
    }
  }
}

} // namespace

extern "C" void kernel_launch(void* const* d_in, const int* in_sizes, int n_in,
                              void* d_out, int out_size, void* d_ws, size_t ws_size,
                              hipStream_t stream) {
  const float* hidden     = (const float*)d_in[0];
  const float* ttu_state  = (const float*)d_in[1];
  const float* W_imp      = (const float*)d_in[2];
  const float* b_imp      = (const float*)d_in[3];
  const float* W_lm       = (const float*)d_in[4];
  const float* W_mod      = (const float*)d_in[5];
  const float* ttu_params = (const float*)d_in[6];
  float* out = (float*)d_out;

  float* imp    = (float*)d_ws;          // 2048 f32
  float* states = imp + S_ * B_;         // 6144 f32  (32 KB total)
  float* final_out = out + (size_t)B_ * S_ * V_;

  const size_t need = 32768 + (size_t)M_ * H_ * 2 + (size_t)VP1_ * H_ * 2;

  if (ws_size >= need) {
    unsigned short* hid_bf = (unsigned short*)((char*)d_ws + 32768);
    unsigned short* wlm_bf = hid_bf + (size_t)M_ * H_;
    cvt_hidden_impulse_kernel<<<M_, 256, 0, stream>>>(hidden, W_imp, b_imp, hid_bf, imp);
    cvt_wlm_scan_kernel<<<2049, 256, 0, stream>>>(W_lm, wlm_bf,
                                                  (long)V_ * H_, (long)VP1_ * H_,
                                                  imp, ttu_state, ttu_params,
                                                  states, final_out);
    const int grid = (VP1_ / 128) * (M_ / 128);   // 393*16 = 6288
    ttu_gemm_bf16_128x32_kernel<<<grid, 256, 0, stream>>>(hid_bf, wlm_bf, states, W_mod, out);
  } else {
    cvt_hidden_impulse_kernel<<<M_, 256, 0, stream>>>(hidden, W_imp, b_imp,
                                                      (unsigned short*)d_ws, imp);
    ttu_scan_kernel<<<1, 64, 0, stream>>>(imp, ttu_state, ttu_params, states, final_out);
    const int grid = ((V_ + 127) / 128) * (M_ / 128);
    ttu_gemm_kernel<<<grid, 256, 0, stream>>>(hidden, W_lm, states, W_mod, out);
  }
}